// Round 1
// baseline (949.272 us; speedup 1.0000x reference)
//
#include <hip/hip_runtime.h>

// Problem constants (B=16, C1=C2=128, H=W=80, K=3, pad=1, stride=1)
#define HH 80
#define WW 80
#define C1 128
#define C2 128
#define NB 16
#define HWSZ 6400      // 80*80
#define KKT 1152       // C1*9

// ---------------------------------------------------------------------------
// Kernel 0: transpose weight (C2, C1*9) -> wT[k][o]  (k = c*9+p)
// ---------------------------------------------------------------------------
__global__ __launch_bounds__(256) void wtrans_kernel(const float* __restrict__ w,
                                                     float* __restrict__ wt) {
  int idx = blockIdx.x * 256 + threadIdx.x;      // 147456 total
  if (idx >= C2 * KKT) return;
  int k = idx >> 7;        // idx / 128
  int o = idx & 127;
  wt[idx] = w[(size_t)o * KKT + k];              // coalesced write, strided read (tiny)
}

// ---------------------------------------------------------------------------
// Kernel 1: offset conv  x(16,128,80,80) * ow(18,128,3,3) -> offs(16,18,80,80)
// 16x16 spatial tile per block, 18 accumulators/thread, LDS-staged x + weights
// ---------------------------------------------------------------------------
__global__ __launch_bounds__(256) void offset_conv_kernel(
    const float* __restrict__ x, const float* __restrict__ ow,
    const float* __restrict__ ob, float* __restrict__ offs) {
  const int b = blockIdx.y;
  const int tile = blockIdx.x;                   // 0..24
  const int th0 = (tile / 5) * 16, tw0 = (tile % 5) * 16;
  const int tid = threadIdx.x;
  const int ty = tid >> 4, tx = tid & 15;
  const int ho = th0 + ty, wo = tw0 + tx;

  __shared__ float xs[4][18][18];                // 4 channels, 16x16 tile + halo
  __shared__ float wsT[4][9][20];                // [c][p][co] co-minor, padded

  float acc[18];
  #pragma unroll
  for (int i = 0; i < 18; i++) acc[i] = ob[i];

  const float* xb = x + (size_t)b * C1 * HWSZ;

  for (int c0 = 0; c0 < C1; c0 += 4) {
    __syncthreads();
    // stage 4 channels of x tile (with halo, zero-padded)
    for (int i = tid; i < 4 * 18 * 18; i += 256) {
      int cc = i / 324;
      int rem = i - cc * 324;
      int r = rem / 18, col = rem - r * 18;
      int gy = th0 - 1 + r, gx = tw0 - 1 + col;
      float v = 0.f;
      if (gy >= 0 && gy < HH && gx >= 0 && gx < WW)
        v = xb[(size_t)(c0 + cc) * HWSZ + gy * WW + gx];
      xs[cc][r][col] = v;
    }
    // stage weights transposed: wsT[cc][p][co] = ow[co][c0+cc][p]
    for (int i = tid; i < 4 * 9 * 18; i += 256) {
      int cc = i / 162;
      int rem = i - cc * 162;
      int p = rem / 18, co = rem - p * 18;
      wsT[cc][p][co] = ow[((size_t)co * C1 + (c0 + cc)) * 9 + p];
    }
    __syncthreads();

    #pragma unroll
    for (int cc = 0; cc < 4; cc++) {
      #pragma unroll
      for (int p = 0; p < 9; p++) {
        float sxp = xs[cc][ty + p / 3][tx + p % 3];
        const float4 w0 = *(const float4*)&wsT[cc][p][0];
        const float4 w1 = *(const float4*)&wsT[cc][p][4];
        const float4 w2 = *(const float4*)&wsT[cc][p][8];
        const float4 w3 = *(const float4*)&wsT[cc][p][12];
        const float2 w4 = *(const float2*)&wsT[cc][p][16];
        acc[0]  += sxp * w0.x;  acc[1]  += sxp * w0.y;
        acc[2]  += sxp * w0.z;  acc[3]  += sxp * w0.w;
        acc[4]  += sxp * w1.x;  acc[5]  += sxp * w1.y;
        acc[6]  += sxp * w1.z;  acc[7]  += sxp * w1.w;
        acc[8]  += sxp * w2.x;  acc[9]  += sxp * w2.y;
        acc[10] += sxp * w2.z;  acc[11] += sxp * w2.w;
        acc[12] += sxp * w3.x;  acc[13] += sxp * w3.y;
        acc[14] += sxp * w3.z;  acc[15] += sxp * w3.w;
        acc[16] += sxp * w4.x;  acc[17] += sxp * w4.y;
      }
    }
  }

  float* op = offs + (size_t)b * 18 * HWSZ + ho * WW + wo;
  #pragma unroll
  for (int co = 0; co < 18; co++) op[(size_t)co * HWSZ] = acc[co];
}

// ---------------------------------------------------------------------------
// Kernel 2: fused bilinear sampling + GEMM (fp32 vector)
// Block: 64 spatial positions (4 rows x 16 cols) x 128 out channels, 256 thr.
// K = 1152 staged in chunks of 32: s_t[32][64] sampled, w_t[32][128] weights.
// Thread computes 4 positions (consecutive cols, one row) x 8 channels.
// ---------------------------------------------------------------------------
__global__ __launch_bounds__(256) void dconv_kernel(
    const float* __restrict__ x, const float* __restrict__ offs,
    const float* __restrict__ wt, const float* __restrict__ bias,
    float* __restrict__ out) {
  const int b = blockIdx.y;
  const int tile = blockIdx.x;                   // 0..99
  const int h0 = (tile / 5) * 4;
  const int w0 = (tile % 5) * 16;
  const int tid = threadIdx.x;

  __shared__ int   cy0[9][64];
  __shared__ int   cx0[9][64];
  __shared__ float cwy[9][64];
  __shared__ float cwx[9][64];
  __shared__ float s_t[32][64];
  __shared__ float w_t[32][128];

  // Phase A: per-(p,pos) bilinear coords (shared by all 128 channels)
  for (int i = tid; i < 9 * 64; i += 256) {
    int p = i >> 6, pos = i & 63;
    int r = pos >> 4, cl = pos & 15;
    int ho = h0 + r, wo = w0 + cl;
    const float* ob = offs + (size_t)b * 18 * HWSZ + ho * WW + wo;
    float dy = ob[(size_t)(2 * p) * HWSZ];
    float dx = ob[(size_t)(2 * p + 1) * HWSZ];
    float py = (float)(ho - 1 + p / 3) + dy;
    float px = (float)(wo - 1 + p % 3) + dx;
    float y0f = floorf(py), x0f = floorf(px);
    cy0[p][pos] = (int)y0f;
    cx0[p][pos] = (int)x0f;
    cwy[p][pos] = py - y0f;
    cwx[p][pos] = px - x0f;
  }
  __syncthreads();

  const int tpos = (tid & 15) * 4;               // 4 consecutive cols, same row
  const int toch = (tid >> 4) * 8;               // 8 output channels

  float acc[4][8];
  #pragma unroll
  for (int i = 0; i < 4; i++)
    #pragma unroll
    for (int j = 0; j < 8; j++) acc[i][j] = 0.f;

  const float* xb = x + (size_t)b * C1 * HWSZ;

  for (int k0 = 0; k0 < KKT; k0 += 32) {
    // fill sampled tile: one wave per k-row, 64 positions
    #pragma unroll
    for (int it = 0; it < 8; it++) {
      int i = tid + it * 256;
      int kk = i >> 6, pos = i & 63;
      int k = k0 + kk;
      int c = k / 9;
      int p = k - c * 9;
      int y0 = cy0[p][pos], x0 = cx0[p][pos];
      float wy1 = cwy[p][pos], wx1 = cwx[p][pos];
      float wy0 = 1.f - wy1, wx0 = 1.f - wx1;
      int y1 = y0 + 1, x1 = x0 + 1;
      float my0 = ((unsigned)y0 < (unsigned)HH) ? 1.f : 0.f;
      float my1 = ((unsigned)y1 < (unsigned)HH) ? 1.f : 0.f;
      float mx0 = ((unsigned)x0 < (unsigned)WW) ? 1.f : 0.f;
      float mx1 = ((unsigned)x1 < (unsigned)WW) ? 1.f : 0.f;
      int y0c = min(max(y0, 0), HH - 1), y1c = min(max(y1, 0), HH - 1);
      int x0c = min(max(x0, 0), WW - 1), x1c = min(max(x1, 0), WW - 1);
      const float* xc = xb + (size_t)c * HWSZ;
      float v00 = xc[y0c * WW + x0c];
      float v01 = xc[y0c * WW + x1c];
      float v10 = xc[y1c * WW + x0c];
      float v11 = xc[y1c * WW + x1c];
      float val = wy0 * (wx0 * my0 * mx0 * v00 + wx1 * my0 * mx1 * v01)
                + wy1 * (wx0 * my1 * mx0 * v10 + wx1 * my1 * mx1 * v11);
      s_t[kk][pos] = val;
    }
    // fill weight tile: linear, fully coalesced float4
    {
      const float4* src = (const float4*)&wt[(size_t)k0 * 128];
      float4* dst = (float4*)&w_t[0][0];
      #pragma unroll
      for (int it = 0; it < 4; it++) dst[tid + it * 256] = src[tid + it * 256];
    }
    __syncthreads();

    #pragma unroll
    for (int kk = 0; kk < 32; kk++) {
      const float4 sv  = *(const float4*)&s_t[kk][tpos];
      const float4 wv0 = *(const float4*)&w_t[kk][toch];
      const float4 wv1 = *(const float4*)&w_t[kk][toch + 4];
      float sa[4] = {sv.x, sv.y, sv.z, sv.w};
      float wa[8] = {wv0.x, wv0.y, wv0.z, wv0.w, wv1.x, wv1.y, wv1.z, wv1.w};
      #pragma unroll
      for (int ii = 0; ii < 4; ii++)
        #pragma unroll
        for (int jj = 0; jj < 8; jj++)
          acc[ii][jj] += sa[ii] * wa[jj];
    }
    __syncthreads();
  }

  // epilogue: 4 consecutive cols in one row -> float4 store per channel
  {
    int r = tpos >> 4, cl = tpos & 15;
    int ho = h0 + r, wo = w0 + cl;
    #pragma unroll
    for (int jj = 0; jj < 8; jj++) {
      int o = toch + jj;
      float bv = bias[o];
      float4 res = make_float4(acc[0][jj] + bv, acc[1][jj] + bv,
                               acc[2][jj] + bv, acc[3][jj] + bv);
      *(float4*)&out[((size_t)b * C2 + o) * HWSZ + ho * WW + wo] = res;
    }
  }
}

// ---------------------------------------------------------------------------
extern "C" void kernel_launch(void* const* d_in, const int* in_sizes, int n_in,
                              void* d_out, int out_size, void* d_ws, size_t ws_size,
                              hipStream_t stream) {
  const float* x    = (const float*)d_in[0];   // (16,128,80,80)
  const float* ow   = (const float*)d_in[1];   // (18,128,3,3)
  const float* ob   = (const float*)d_in[2];   // (18,)
  const float* wgt  = (const float*)d_in[3];   // (128,128,3,3)
  const float* bias = (const float*)d_in[4];   // (128,)
  float* out = (float*)d_out;                  // (16,128,80,80)

  float* offs = (float*)d_ws;                  // 16*18*6400 = 1,843,200 floats
  float* wtr  = offs + (size_t)NB * 18 * HWSZ; // 1152*128  =   147,456 floats

  // Kernel 0: weight transpose
  wtrans_kernel<<<dim3(576), dim3(256), 0, stream>>>(wgt, wtr);

  // Kernel 1: offset conv
  offset_conv_kernel<<<dim3(25, NB), dim3(256), 0, stream>>>(x, ow, ob, offs);

  // Kernel 2: fused sample + GEMM
  dconv_kernel<<<dim3(100, NB), dim3(256), 0, stream>>>(x, offs, wtr, bias, out);
}

// Round 2
// 745.126 us; speedup vs baseline: 1.2740x; 1.2740x over previous
//
#include <hip/hip_runtime.h>

// Problem constants (B=16, C1=C2=128, H=W=80, K=3, pad=1, stride=1)
#define HH 80
#define WW 80
#define C1 128
#define C2 128
#define NB 16
#define HWSZ 6400      // 80*80
#define KKT 1152       // C1*9

typedef __attribute__((ext_vector_type(8))) short bf16x8;
typedef __attribute__((ext_vector_type(4))) float f32x4;

__device__ inline ushort f2bf(float f) {
  unsigned u = __float_as_uint(f);
  return (ushort)((u + 0x7FFFu + ((u >> 16) & 1u)) >> 16);
}

// ---------------------------------------------------------------------------
// Kernel 0: weight (C2=128, K=1152) fp32 -> bf16 in MFMA chunk order:
//   wbf[kt][kg][ch][j]  (kt=k/32, kg=(k%32)/8, j=k%8), 36*4*128*8 = 147456
// so each 32-k chunk is a contiguous 8 KB block matching the LDS layout.
// ---------------------------------------------------------------------------
__global__ __launch_bounds__(256) void wprep_kernel(const float* __restrict__ w,
                                                    ushort* __restrict__ wbf) {
  int o = blockIdx.x * 256 + threadIdx.x;        // 147456 total
  if (o >= C2 * KKT) return;
  int j  = o & 7;
  int ch = (o >> 3) & 127;
  int kg = (o >> 10) & 3;
  int kt = o >> 12;
  int k  = kt * 32 + kg * 8 + j;
  wbf[o] = f2bf(w[(size_t)ch * KKT + k]);
}

// ---------------------------------------------------------------------------
// Kernel 1: offset conv  x(16,128,80,80) * ow(18,128,3,3) -> offs(16,18,80,80)
// (unchanged from R1 — not the bottleneck yet)
// ---------------------------------------------------------------------------
__global__ __launch_bounds__(256) void offset_conv_kernel(
    const float* __restrict__ x, const float* __restrict__ ow,
    const float* __restrict__ ob, float* __restrict__ offs) {
  const int b = blockIdx.y;
  const int tile = blockIdx.x;                   // 0..24
  const int th0 = (tile / 5) * 16, tw0 = (tile % 5) * 16;
  const int tid = threadIdx.x;
  const int ty = tid >> 4, tx = tid & 15;
  const int ho = th0 + ty, wo = tw0 + tx;

  __shared__ float xs[4][18][18];
  __shared__ float wsT[4][9][20];

  float acc[18];
  #pragma unroll
  for (int i = 0; i < 18; i++) acc[i] = ob[i];

  const float* xb = x + (size_t)b * C1 * HWSZ;

  for (int c0 = 0; c0 < C1; c0 += 4) {
    __syncthreads();
    for (int i = tid; i < 4 * 18 * 18; i += 256) {
      int cc = i / 324;
      int rem = i - cc * 324;
      int r = rem / 18, col = rem - r * 18;
      int gy = th0 - 1 + r, gx = tw0 - 1 + col;
      float v = 0.f;
      if (gy >= 0 && gy < HH && gx >= 0 && gx < WW)
        v = xb[(size_t)(c0 + cc) * HWSZ + gy * WW + gx];
      xs[cc][r][col] = v;
    }
    for (int i = tid; i < 4 * 9 * 18; i += 256) {
      int cc = i / 162;
      int rem = i - cc * 162;
      int p = rem / 18, co = rem - p * 18;
      wsT[cc][p][co] = ow[((size_t)co * C1 + (c0 + cc)) * 9 + p];
    }
    __syncthreads();

    #pragma unroll
    for (int cc = 0; cc < 4; cc++) {
      #pragma unroll
      for (int p = 0; p < 9; p++) {
        float sxp = xs[cc][ty + p / 3][tx + p % 3];
        const float4 w0 = *(const float4*)&wsT[cc][p][0];
        const float4 w1 = *(const float4*)&wsT[cc][p][4];
        const float4 w2 = *(const float4*)&wsT[cc][p][8];
        const float4 w3 = *(const float4*)&wsT[cc][p][12];
        const float2 w4 = *(const float2*)&wsT[cc][p][16];
        acc[0]  += sxp * w0.x;  acc[1]  += sxp * w0.y;
        acc[2]  += sxp * w0.z;  acc[3]  += sxp * w0.w;
        acc[4]  += sxp * w1.x;  acc[5]  += sxp * w1.y;
        acc[6]  += sxp * w1.z;  acc[7]  += sxp * w1.w;
        acc[8]  += sxp * w2.x;  acc[9]  += sxp * w2.y;
        acc[10] += sxp * w2.z;  acc[11] += sxp * w2.w;
        acc[12] += sxp * w3.x;  acc[13] += sxp * w3.y;
        acc[14] += sxp * w3.z;  acc[15] += sxp * w3.w;
        acc[16] += sxp * w4.x;  acc[17] += sxp * w4.y;
      }
    }
  }

  float* op = offs + (size_t)b * 18 * HWSZ + ho * WW + wo;
  #pragma unroll
  for (int co = 0; co < 18; co++) op[(size_t)co * HWSZ] = acc[co];
}

// ---------------------------------------------------------------------------
// Kernel 2: fused bilinear sampling + bf16 MFMA GEMM
// Block = 64 positions (4 rows x 16 cols) x 128 out-channels, 256 thr / 4 waves.
// Wave w: sampler role = kgroup w (8 k-values x 64 positions per chunk);
//         GEMM role    = positions [w*16, w*16+16) x all 128 channels
//         (8 MFMA tiles of 16x16x32_bf16, acc 8 x f32x4).
// LDS tiles laid out [kg][row][8] so every fragment read/write is a 16B-aligned
// contiguous-256B-per-phase ds_*_b128 (bank-conflict-free).
// ---------------------------------------------------------------------------
__global__ __launch_bounds__(256) void dconv_mfma_kernel(
    const float* __restrict__ x, const float* __restrict__ offs,
    const ushort* __restrict__ wbf, const float* __restrict__ bias,
    float* __restrict__ out) {
  const int b = blockIdx.y;
  const int tile = blockIdx.x;                   // 0..99
  const int h0 = (tile / 5) * 4;
  const int w0 = (tile % 5) * 16;
  const int tid = threadIdx.x;
  const int lane = tid & 63;
  const int wave = tid >> 6;

  __shared__ float4 crd[9][64];                  // {y0f, x0f, wy1, wx1} 9216 B
  __shared__ ushort s_t[4][64][8];               // [kg][pos][j] 4096 B
  __shared__ ushort w_t[4][128][8];              // [kg][ch][j]  8192 B

  // Phase A: per-(p,pos) bilinear coords (shared across all channels & chunks)
  for (int i = tid; i < 9 * 64; i += 256) {
    int p = i >> 6, pos = i & 63;
    int r = pos >> 4, cl = pos & 15;
    int ho = h0 + r, wo = w0 + cl;
    const float* ob = offs + (size_t)b * 18 * HWSZ + ho * WW + wo;
    float dy = ob[(size_t)(2 * p) * HWSZ];
    float dx = ob[(size_t)(2 * p + 1) * HWSZ];
    float py = (float)(ho - 1 + p / 3) + dy;
    float px = (float)(wo - 1 + p % 3) + dx;
    float y0f = floorf(py), x0f = floorf(px);
    crd[p][pos] = make_float4(y0f, x0f, py - y0f, px - x0f);
  }
  __syncthreads();

  f32x4 acc[8];
  #pragma unroll
  for (int mt = 0; mt < 8; mt++) acc[mt] = (f32x4){0.f, 0.f, 0.f, 0.f};

  const float* xb = x + (size_t)b * C1 * HWSZ;
  const int pos = lane;                          // sampler position
  const int kg = wave;                           // sampler k-group

  for (int kt = 0; kt < 36; ++kt) {
    const int k0 = kt * 32;

    // ---- sample 8 k-values for this thread's position into registers
    union { ushort u[8]; uint4 v; } pk;
    #pragma unroll
    for (int j = 0; j < 8; ++j) {
      int k = k0 + (kg << 3) + j;
      int c = k / 9;
      int p = k - c * 9;
      float4 cd = crd[p][pos];
      int y0 = (int)cd.x, x0 = (int)cd.y;
      float wy1 = cd.z, wx1 = cd.w;
      float wy0 = 1.f - wy1, wx0 = 1.f - wx1;
      int y1 = y0 + 1, x1 = x0 + 1;
      float my0 = ((unsigned)y0 < (unsigned)HH) ? 1.f : 0.f;
      float my1 = ((unsigned)y1 < (unsigned)HH) ? 1.f : 0.f;
      float mx0 = ((unsigned)x0 < (unsigned)WW) ? 1.f : 0.f;
      float mx1 = ((unsigned)x1 < (unsigned)WW) ? 1.f : 0.f;
      int y0c = min(max(y0, 0), HH - 1), y1c = min(max(y1, 0), HH - 1);
      int x0c = min(max(x0, 0), WW - 1), x1c = min(max(x1, 0), WW - 1);
      const float* xc = xb + (size_t)c * HWSZ;
      float v00 = xc[y0c * WW + x0c];
      float v01 = xc[y0c * WW + x1c];
      float v10 = xc[y1c * WW + x0c];
      float v11 = xc[y1c * WW + x1c];
      float val = wy0 * (wx0 * my0 * mx0 * v00 + wx1 * my0 * mx1 * v01)
                + wy1 * (wx0 * my1 * mx0 * v10 + wx1 * my1 * mx1 * v11);
      pk.u[j] = f2bf(val);
    }

    // ---- fetch this chunk's weights (linear 8 KB) into registers
    const uint4* wsrc = (const uint4*)(wbf + (size_t)kt * 4096);
    uint4 wreg0 = wsrc[tid];
    uint4 wreg1 = wsrc[tid + 256];

    __syncthreads();   // all waves done reading previous chunk's tiles

    ((uint4*)s_t)[kg * 64 + pos] = pk.v;         // one b128 write
    ((uint4*)w_t)[tid] = wreg0;
    ((uint4*)w_t)[tid + 256] = wreg1;

    __syncthreads();   // tiles ready

    // ---- MFMA: B frag (16 positions), 8 A frags (128 channels)
    const int q = lane >> 4, c15 = lane & 15;
    bf16x8 bfrag = *(const bf16x8*)&s_t[q][wave * 16 + c15][0];
    #pragma unroll
    for (int mt = 0; mt < 8; mt++) {
      bf16x8 afrag = *(const bf16x8*)&w_t[q][mt * 16 + c15][0];
      acc[mt] = __builtin_amdgcn_mfma_f32_16x16x32_bf16(afrag, bfrag, acc[mt], 0, 0, 0);
    }
  }

  // ---- epilogue: D layout col(n=pos)=lane&15, row(m=ch)=(lane>>4)*4+reg
  {
    const int q = lane >> 4, c15 = lane & 15;
    const int ho = h0 + wave;                    // wave's spatial row
    const int wo = w0 + c15;
    #pragma unroll
    for (int mt = 0; mt < 8; mt++) {
      #pragma unroll
      for (int r = 0; r < 4; r++) {
        int ch = mt * 16 + q * 4 + r;
        out[((size_t)b * C2 + ch) * HWSZ + ho * WW + wo] = acc[mt][r] + bias[ch];
      }
    }
  }
}

// ---------------------------------------------------------------------------
extern "C" void kernel_launch(void* const* d_in, const int* in_sizes, int n_in,
                              void* d_out, int out_size, void* d_ws, size_t ws_size,
                              hipStream_t stream) {
  const float* x    = (const float*)d_in[0];   // (16,128,80,80)
  const float* ow   = (const float*)d_in[1];   // (18,128,3,3)
  const float* ob   = (const float*)d_in[2];   // (18,)
  const float* wgt  = (const float*)d_in[3];   // (128,128,3,3)
  const float* bias = (const float*)d_in[4];   // (128,)
  float* out = (float*)d_out;                  // (16,128,80,80)

  float*  offs = (float*)d_ws;                    // 1,843,200 floats (7.37 MB)
  ushort* wbf  = (ushort*)(offs + (size_t)NB * 18 * HWSZ);  // 147,456 bf16

  wprep_kernel<<<dim3(576), dim3(256), 0, stream>>>(wgt, wbf);
  offset_conv_kernel<<<dim3(25, NB), dim3(256), 0, stream>>>(x, ow, ob, offs);
  dconv_mfma_kernel<<<dim3(100, NB), dim3(256), 0, stream>>>(x, offs, wbf, bias, out);
}

// Round 3
// 277.493 us; speedup vs baseline: 3.4209x; 2.6852x over previous
//
#include <hip/hip_runtime.h>

// Problem constants (B=16, C1=C2=128, H=W=80, K=3, pad=1, stride=1)
#define HH 80
#define WW 80
#define C1 128
#define C2 128
#define NB 16
#define HWSZ 6400      // 80*80
#define KKT 1152       // C1*9 (GEMM K, reordered as k' = p*128 + c)

typedef __attribute__((ext_vector_type(8))) short bf16x8;
typedef __attribute__((ext_vector_type(4))) float f32x4;

__device__ inline ushort f2bf(float f) {
  unsigned u = __float_as_uint(f);
  return (ushort)((u + 0x7FFFu + ((u >> 16) & 1u)) >> 16);
}
__device__ inline float bf2f(ushort u) {
  return __uint_as_float(((unsigned)u) << 16);
}

// ---------------------------------------------------------------------------
// Kernel A: transpose x (b,c,hw) f32 -> xt (b,hw,c) bf16.  64hw x 64c tiles.
// ---------------------------------------------------------------------------
__global__ __launch_bounds__(256) void xpose_kernel(const float* __restrict__ x,
                                                    ushort* __restrict__ xt) {
  const int b = blockIdx.z;
  const int c0 = blockIdx.y * 64;
  const int hw0 = blockIdx.x * 64;
  const int tid = threadIdx.x;
  const int lane = tid & 63;

  __shared__ float ts[64][65];

  #pragma unroll
  for (int it = 0; it < 16; it++) {
    int cl = (tid >> 6) + it * 4;
    ts[cl][lane] = x[((size_t)(b * C1 + c0 + cl)) * HWSZ + hw0 + lane];
  }
  __syncthreads();

  #pragma unroll
  for (int it = 0; it < 2; it++) {
    int u = tid + it * 256;
    int j = u >> 3, cg = u & 7;
    union { uint4 v; ushort s[8]; } pk;
    #pragma unroll
    for (int k = 0; k < 8; k++) pk.s[k] = f2bf(ts[cg * 8 + k][j]);
    *(uint4*)(xt + ((size_t)b * HWSZ + hw0 + j) * C1 + c0 + cg * 8) = pk.v;
  }
}

// ---------------------------------------------------------------------------
// Kernel B: main weights (C2,1152) f32 -> bf16, k' = p*128+c order, chunked:
//   wbf[kt][kg][ch][j], k' = kt*32+kg*8+j, p = k'>>7, c = k'&127
// ---------------------------------------------------------------------------
__global__ __launch_bounds__(256) void wprep_kernel(const float* __restrict__ w,
                                                    ushort* __restrict__ wbf) {
  int o = blockIdx.x * 256 + threadIdx.x;        // 147456
  if (o >= C2 * KKT) return;
  int j  = o & 7;
  int ch = (o >> 3) & 127;
  int kgt = o >> 10;                             // kt*4+kg
  int kp = kgt * 32 + ((o >> 3) & 0) + (kgt & 0); // silence nothing
  int k2 = (kgt) * 32 + ( ( (o) & 7) ) + 0;      // base
  (void)kp; (void)k2;
  int kq = kgt * 32 + ((o & 7));                 // not final; recompute cleanly:
  (void)kq;
  int kt = o >> 12;
  int kg = (o >> 10) & 3;
  int kprime = kt * 32 + kg * 8 + j;
  int p = kprime >> 7;
  int c = kprime & 127;
  wbf[o] = f2bf(w[(size_t)ch * KKT + c * 9 + p]);
}

// ---------------------------------------------------------------------------
// Kernel C: offset-conv weights (18,128,3,3) f32 -> bf16 padded to 32 ch:
//   wobf[kt][kg][ch32][j], same k' order; ch >= 18 -> 0
// ---------------------------------------------------------------------------
__global__ __launch_bounds__(256) void oprep_kernel(const float* __restrict__ ow,
                                                    ushort* __restrict__ wobf) {
  int o = blockIdx.x * 256 + threadIdx.x;        // 36864
  if (o >= 32 * KKT) return;
  int j  = o & 7;
  int ch = (o >> 3) & 31;
  int kt = o >> 10;
  int kg = (o >> 8) & 3;
  int kprime = kt * 32 + kg * 8 + j;
  int p = kprime >> 7;
  int c = kprime & 127;
  wobf[o] = (ch < 18) ? f2bf(ow[(size_t)ch * KKT + c * 9 + p]) : (ushort)0;
}

// ---------------------------------------------------------------------------
// Kernel D: offset conv via shifted-read implicit GEMM over xt (bf16 MFMA).
// Block = 64 pos (4 rows x 16 cols) x 32 out-ch (18 used), 256 thr / 4 waves.
// ---------------------------------------------------------------------------
__global__ __launch_bounds__(256) void offset_mfma_kernel(
    const ushort* __restrict__ xt, const ushort* __restrict__ wobf,
    const float* __restrict__ ob, float* __restrict__ offs) {
  const int b = blockIdx.y;
  const int tile = blockIdx.x;                   // 0..99
  const int h0 = (tile / 5) * 4;
  const int w0 = (tile % 5) * 16;
  const int tid = threadIdx.x;
  const int lane = tid & 63;
  const int wave = tid >> 6;
  const int pl = lane & 15, cg = lane >> 4;      // sampler mapping
  const int spos = wave * 16 + pl;

  __shared__ ushort s_t[4][64][8];               // [kg][pos][j] 4 KB
  __shared__ ushort w_t[4][32][8];               // [kg][ch][j]  2 KB

  f32x4 acc0 = {0.f, 0.f, 0.f, 0.f}, acc1 = {0.f, 0.f, 0.f, 0.f};
  const ushort* xtb = xt + (size_t)b * HWSZ * C1;

  for (int kt = 0; kt < 36; ++kt) {
    const int p = kt >> 2, c0 = (kt & 3) << 5;
    const int row = h0 + (spos >> 4) + (p / 3) - 1;
    const int col = w0 + (spos & 15) + (p % 3) - 1;
    uint4 v = {0u, 0u, 0u, 0u};
    if ((unsigned)row < (unsigned)HH && (unsigned)col < (unsigned)WW)
      v = *(const uint4*)(xtb + ((size_t)row * WW + col) * C1 + c0 + cg * 8);
    uint4 wpre;
    if (tid < 128) wpre = ((const uint4*)(wobf + (size_t)kt * 1024))[tid];

    __syncthreads();
    ((uint4*)s_t)[cg * 64 + spos] = v;
    if (tid < 128) ((uint4*)w_t)[tid] = wpre;
    __syncthreads();

    const int q = lane >> 4, c15 = lane & 15;
    bf16x8 bfrag = *(const bf16x8*)&s_t[q][wave * 16 + c15][0];
    bf16x8 a0 = *(const bf16x8*)&w_t[q][c15][0];
    bf16x8 a1 = *(const bf16x8*)&w_t[q][16 + c15][0];
    acc0 = __builtin_amdgcn_mfma_f32_16x16x32_bf16(a0, bfrag, acc0, 0, 0, 0);
    acc1 = __builtin_amdgcn_mfma_f32_16x16x32_bf16(a1, bfrag, acc1, 0, 0, 0);
  }

  // epilogue: D col = lane&15 (pos), row = (lane>>4)*4+reg (ch)
  {
    const int q = lane >> 4, c15 = lane & 15;
    const int ho = h0 + wave, wo = w0 + c15;
    #pragma unroll
    for (int r = 0; r < 4; r++) {
      int ch = q * 4 + r;
      if (ch < 18)
        offs[((size_t)b * 18 + ch) * HWSZ + ho * WW + wo] = acc0[r] + ob[ch];
      int ch1 = 16 + q * 4 + r;
      if (ch1 < 18)
        offs[((size_t)b * 18 + ch1) * HWSZ + ho * WW + wo] = acc1[r] + ob[ch1];
    }
  }
}

// ---------------------------------------------------------------------------
// Kernel E: fused bilinear sampling (NHWC bf16, coalesced 16B loads) + MFMA.
// Block = 64 pos x 128 out-ch, 256 thr / 4 waves. K chunks of 32 (one p per
// 4 chunks, 32 channels each). Thread samples 8 contiguous channels of one
// pos: 4 x dwordx4 corner loads, separable mask-folded bilinear weights.
// ---------------------------------------------------------------------------
__global__ __launch_bounds__(256) void dconv_mfma_kernel(
    const ushort* __restrict__ xt, const float* __restrict__ offs,
    const ushort* __restrict__ wbf, const float* __restrict__ bias,
    float* __restrict__ out) {
  const int b = blockIdx.y;
  const int tile = blockIdx.x;                   // 0..99
  const int h0 = (tile / 5) * 4;
  const int w0 = (tile % 5) * 16;
  const int tid = threadIdx.x;
  const int lane = tid & 63;
  const int wave = tid >> 6;
  const int pl = lane & 15, cg = lane >> 4;
  const int spos = wave * 16 + pl;

  __shared__ float4 crd[9][64];                  // {y0f,x0f,wy1,wx1} 9216 B
  __shared__ ushort s_t[4][64][8];               // 4 KB
  __shared__ ushort w_t[4][128][8];              // 8 KB

  // Phase A: per-(p,pos) coords
  for (int i = tid; i < 9 * 64; i += 256) {
    int p = i >> 6, pos = i & 63;
    int r = pos >> 4, cl = pos & 15;
    int ho = h0 + r, wo = w0 + cl;
    const float* obp = offs + (size_t)b * 18 * HWSZ + ho * WW + wo;
    float dy = obp[(size_t)(2 * p) * HWSZ];
    float dx = obp[(size_t)(2 * p + 1) * HWSZ];
    float py = (float)(ho - 1 + p / 3) + dy;
    float px = (float)(wo - 1 + p % 3) + dx;
    float y0f = floorf(py), x0f = floorf(px);
    crd[p][pos] = make_float4(y0f, x0f, py - y0f, px - x0f);
  }
  __syncthreads();

  f32x4 acc[8];
  #pragma unroll
  for (int mt = 0; mt < 8; mt++) acc[mt] = (f32x4){0.f, 0.f, 0.f, 0.f};

  const ushort* xtb = xt + (size_t)b * HWSZ * C1;

  // persistent geometry (recomputed when p changes, every 4 chunks)
  float fy0 = 0.f, fy1 = 0.f, fx0 = 0.f, fx1 = 0.f;
  int o00 = 0, o01 = 0, o10 = 0, o11 = 0;

  for (int kt = 0; kt < 36; ++kt) {
    const int c0 = (kt & 3) << 5;
    if ((kt & 3) == 0) {
      int p = kt >> 2;
      float4 cd = crd[p][spos];
      int y0 = (int)cd.x, x0 = (int)cd.y;
      float wy1 = cd.z, wx1 = cd.w;
      fy0 = ((unsigned)y0 < (unsigned)HH) ? (1.f - wy1) : 0.f;
      fy1 = ((unsigned)(y0 + 1) < (unsigned)HH) ? wy1 : 0.f;
      fx0 = ((unsigned)x0 < (unsigned)WW) ? (1.f - wx1) : 0.f;
      fx1 = ((unsigned)(x0 + 1) < (unsigned)WW) ? wx1 : 0.f;
      int r0 = min(max(y0, 0), HH - 1), r1 = min(max(y0 + 1, 0), HH - 1);
      int q0 = min(max(x0, 0), WW - 1), q1 = min(max(x0 + 1, 0), WW - 1);
      o00 = (r0 * WW + q0) * C1; o01 = (r0 * WW + q1) * C1;
      o10 = (r1 * WW + q0) * C1; o11 = (r1 * WW + q1) * C1;
    }

    // ---- 4 coalesced 16B corner loads (8 contiguous channels)
    const ushort* cp = xtb + c0 + cg * 8;
    union { uint4 v; ushort s[8]; } a00, a01, a10, a11, pk;
    a00.v = *(const uint4*)(cp + o00);
    a01.v = *(const uint4*)(cp + o01);
    a10.v = *(const uint4*)(cp + o10);
    a11.v = *(const uint4*)(cp + o11);

    // ---- weights for this chunk (linear 8 KB)
    const uint4* wsrc = (const uint4*)(wbf + (size_t)kt * 4096);
    uint4 wreg0 = wsrc[tid];
    uint4 wreg1 = wsrc[tid + 256];

    // ---- separable bilinear combine, bf16 pack
    #pragma unroll
    for (int j = 0; j < 8; ++j) {
      float top = fx0 * bf2f(a00.s[j]) + fx1 * bf2f(a01.s[j]);
      float bot = fx0 * bf2f(a10.s[j]) + fx1 * bf2f(a11.s[j]);
      pk.s[j] = f2bf(fy0 * top + fy1 * bot);
    }

    __syncthreads();
    ((uint4*)s_t)[cg * 64 + spos] = pk.v;
    ((uint4*)w_t)[tid] = wreg0;
    ((uint4*)w_t)[tid + 256] = wreg1;
    __syncthreads();

    // ---- MFMA: B frag (16 pos), 8 A frags (128 ch)
    const int q = lane >> 4, c15 = lane & 15;
    bf16x8 bfrag = *(const bf16x8*)&s_t[q][wave * 16 + c15][0];
    #pragma unroll
    for (int mt = 0; mt < 8; mt++) {
      bf16x8 afrag = *(const bf16x8*)&w_t[q][mt * 16 + c15][0];
      acc[mt] = __builtin_amdgcn_mfma_f32_16x16x32_bf16(afrag, bfrag, acc[mt], 0, 0, 0);
    }
  }

  // ---- epilogue
  {
    const int q = lane >> 4, c15 = lane & 15;
    const int ho = h0 + wave, wo = w0 + c15;
    #pragma unroll
    for (int mt = 0; mt < 8; mt++) {
      #pragma unroll
      for (int r = 0; r < 4; r++) {
        int ch = mt * 16 + q * 4 + r;
        out[((size_t)b * C2 + ch) * HWSZ + ho * WW + wo] = acc[mt][r] + bias[ch];
      }
    }
  }
}

// ---------------------------------------------------------------------------
extern "C" void kernel_launch(void* const* d_in, const int* in_sizes, int n_in,
                              void* d_out, int out_size, void* d_ws, size_t ws_size,
                              hipStream_t stream) {
  const float* x    = (const float*)d_in[0];   // (16,128,80,80)
  const float* ow   = (const float*)d_in[1];   // (18,128,3,3)
  const float* ob   = (const float*)d_in[2];   // (18,)
  const float* wgt  = (const float*)d_in[3];   // (128,128,3,3)
  const float* bias = (const float*)d_in[4];   // (128,)
  float* out = (float*)d_out;                  // (16,128,80,80)

  // workspace layout (xt first for 16B alignment)
  ushort* xt   = (ushort*)d_ws;                          // 16*6400*128 bf16 = 26.2 MB
  float*  offs = (float*)((char*)d_ws + 26214400);       // 16*18*6400 f32 = 7.37 MB
  ushort* wbf  = (ushort*)((char*)d_ws + 26214400 + 7372800);           // 147456 bf16
  ushort* wobf = (ushort*)((char*)d_ws + 26214400 + 7372800 + 294912);  // 36864 bf16

  wprep_kernel<<<dim3(576), dim3(256), 0, stream>>>(wgt, wbf);
  oprep_kernel<<<dim3(144), dim3(256), 0, stream>>>(ow, wobf);
  xpose_kernel<<<dim3(100, 2, NB), dim3(256), 0, stream>>>(x, xt);
  offset_mfma_kernel<<<dim3(100, NB), dim3(256), 0, stream>>>(xt, wobf, ob, offs);
  dconv_mfma_kernel<<<dim3(100, NB), dim3(256), 0, stream>>>(xt, offs, wbf, bias, out);
}

// Round 4
// 275.556 us; speedup vs baseline: 3.4449x; 1.0070x over previous
//
#include <hip/hip_runtime.h>

// Problem constants (B=16, C1=C2=128, H=W=80, K=3, pad=1, stride=1)
#define HH 80
#define WW 80
#define C1 128
#define C2 128
#define NB 16
#define HWSZ 6400      // 80*80
#define KKT 1152       // C1*9 (GEMM K, reordered as k' = p*128 + c)

typedef __attribute__((ext_vector_type(8))) short bf16x8;
typedef __attribute__((ext_vector_type(4))) float f32x4;

__device__ inline ushort f2bf(float f) {
  unsigned u = __float_as_uint(f);
  return (ushort)((u + 0x7FFFu + ((u >> 16) & 1u)) >> 16);
}
__device__ inline float bf2f(ushort u) {
  return __uint_as_float(((unsigned)u) << 16);
}

// ---------------------------------------------------------------------------
// Kernel A: transpose x (b,c,hw) f32 -> xt (b,hw,c) bf16.  64hw x 64c tiles.
// ---------------------------------------------------------------------------
__global__ __launch_bounds__(256) void xpose_kernel(const float* __restrict__ x,
                                                    ushort* __restrict__ xt) {
  const int b = blockIdx.z;
  const int c0 = blockIdx.y * 64;
  const int hw0 = blockIdx.x * 64;
  const int tid = threadIdx.x;
  const int lane = tid & 63;

  __shared__ float ts[64][65];

  #pragma unroll
  for (int it = 0; it < 16; it++) {
    int cl = (tid >> 6) + it * 4;
    ts[cl][lane] = x[((size_t)(b * C1 + c0 + cl)) * HWSZ + hw0 + lane];
  }
  __syncthreads();

  #pragma unroll
  for (int it = 0; it < 2; it++) {
    int u = tid + it * 256;
    int j = u >> 3, cg = u & 7;
    union { uint4 v; ushort s[8]; } pk;
    #pragma unroll
    for (int k = 0; k < 8; k++) pk.s[k] = f2bf(ts[cg * 8 + k][j]);
    *(uint4*)(xt + ((size_t)b * HWSZ + hw0 + j) * C1 + c0 + cg * 8) = pk.v;
  }
}

// ---------------------------------------------------------------------------
// Kernel B: combined weight prep.
//  wbf  [kt][kg][ch128][j] : main weights, k' = p*128+c order (147456)
//  wobf [kt][kg][ch32][j]  : offset-conv weights padded to 32 ch (36864)
// ---------------------------------------------------------------------------
__global__ __launch_bounds__(256) void prep_kernel(const float* __restrict__ w,
                                                   const float* __restrict__ ow,
                                                   ushort* __restrict__ wbf,
                                                   ushort* __restrict__ wobf) {
  int o = blockIdx.x * 256 + threadIdx.x;        // 184320 total
  if (o < C2 * KKT) {
    int j  = o & 7;
    int ch = (o >> 3) & 127;
    int kt = o >> 12;
    int kg = (o >> 10) & 3;
    int kprime = kt * 32 + kg * 8 + j;
    int p = kprime >> 7;
    int c = kprime & 127;
    wbf[o] = f2bf(w[(size_t)ch * KKT + c * 9 + p]);
  } else if (o < C2 * KKT + 32 * KKT) {
    int o2 = o - C2 * KKT;
    int j  = o2 & 7;
    int ch = (o2 >> 3) & 31;
    int kt = o2 >> 10;
    int kg = (o2 >> 8) & 3;
    int kprime = kt * 32 + kg * 8 + j;
    int p = kprime >> 7;
    int c = kprime & 127;
    wobf[o2] = (ch < 18) ? f2bf(ow[(size_t)ch * KKT + c * 9 + p]) : (ushort)0;
  }
}

// ---------------------------------------------------------------------------
// Kernel C: offset conv via shifted-read implicit GEMM over xt (bf16 MFMA).
// 1-D grid, bid = tile*16 + batch  =>  XCD(bid%8) = batch%8 (L2 locality).
// Software-pipelined: chunk kt+1 loads issue before chunk kt's barrier.
// ---------------------------------------------------------------------------
__global__ __launch_bounds__(256) void offset_mfma_kernel(
    const ushort* __restrict__ xt, const ushort* __restrict__ wobf,
    const float* __restrict__ ob, float* __restrict__ offs) {
  const int bid = blockIdx.x;                    // 0..1599
  const int b = bid & 15;
  const int tile = bid >> 4;                     // 0..99
  const int h0 = (tile / 5) * 4;
  const int w0 = (tile % 5) * 16;
  const int tid = threadIdx.x;
  const int lane = tid & 63;
  const int wave = tid >> 6;
  const int pl = lane & 15, cg = lane >> 4;
  const int spos = wave * 16 + pl;

  __shared__ ushort s_t[4][64][8];               // 4 KB
  __shared__ ushort w_t[4][32][8];               // 2 KB

  f32x4 acc0 = {0.f, 0.f, 0.f, 0.f}, acc1 = {0.f, 0.f, 0.f, 0.f};
  const ushort* xtb = xt + (size_t)b * HWSZ * C1;

  auto shifted_load = [&](int kt) -> uint4 {
    const int p = kt >> 2, c0 = (kt & 3) << 5;
    const int row = h0 + (spos >> 4) + (p / 3) - 1;
    const int col = w0 + (spos & 15) + (p % 3) - 1;
    uint4 v = {0u, 0u, 0u, 0u};
    if ((unsigned)row < (unsigned)HH && (unsigned)col < (unsigned)WW)
      v = *(const uint4*)(xtb + ((size_t)row * WW + col) * C1 + c0 + cg * 8);
    return v;
  };

  uint4 cv = shifted_load(0);
  uint4 cw = {0u, 0u, 0u, 0u};
  if (tid < 128) cw = ((const uint4*)wobf)[tid];

  #pragma unroll 4
  for (int kt = 0; kt < 36; ++kt) {
    uint4 nv = {0u, 0u, 0u, 0u}, nw = {0u, 0u, 0u, 0u};
    if (kt < 35) {
      nv = shifted_load(kt + 1);
      if (tid < 128) nw = ((const uint4*)(wobf + (size_t)(kt + 1) * 1024))[tid];
    }

    __syncthreads();
    ((uint4*)s_t)[cg * 64 + spos] = cv;
    if (tid < 128) ((uint4*)w_t)[tid] = cw;
    __syncthreads();

    const int q = lane >> 4, c15 = lane & 15;
    bf16x8 bfrag = *(const bf16x8*)&s_t[q][wave * 16 + c15][0];
    bf16x8 a0 = *(const bf16x8*)&w_t[q][c15][0];
    bf16x8 a1 = *(const bf16x8*)&w_t[q][16 + c15][0];
    acc0 = __builtin_amdgcn_mfma_f32_16x16x32_bf16(a0, bfrag, acc0, 0, 0, 0);
    acc1 = __builtin_amdgcn_mfma_f32_16x16x32_bf16(a1, bfrag, acc1, 0, 0, 0);

    cv = nv; cw = nw;
  }

  // epilogue: D col = lane&15 (pos), row = (lane>>4)*4+reg (ch)
  {
    const int q = lane >> 4, c15 = lane & 15;
    const int ho = h0 + wave, wo = w0 + c15;
    #pragma unroll
    for (int r = 0; r < 4; r++) {
      int ch = q * 4 + r;
      if (ch < 18)
        offs[((size_t)b * 18 + ch) * HWSZ + ho * WW + wo] = acc0[r] + ob[ch];
      int ch1 = 16 + q * 4 + r;
      if (ch1 < 18)
        offs[((size_t)b * 18 + ch1) * HWSZ + ho * WW + wo] = acc1[r] + ob[ch1];
    }
  }
}

// ---------------------------------------------------------------------------
// Kernel D: fused bilinear sampling (NHWC bf16) + MFMA, XCD-swizzled and
// software-pipelined (corner+weight loads one chunk ahead).
// ---------------------------------------------------------------------------
struct Geo { float fy0, fy1, fx0, fx1; int o00, o01, o10, o11; };

__device__ inline Geo make_geo(float4 cd) {
  Geo g;
  int y0 = (int)cd.x, x0 = (int)cd.y;
  float wy1 = cd.z, wx1 = cd.w;
  g.fy0 = ((unsigned)y0 < (unsigned)HH) ? (1.f - wy1) : 0.f;
  g.fy1 = ((unsigned)(y0 + 1) < (unsigned)HH) ? wy1 : 0.f;
  g.fx0 = ((unsigned)x0 < (unsigned)WW) ? (1.f - wx1) : 0.f;
  g.fx1 = ((unsigned)(x0 + 1) < (unsigned)WW) ? wx1 : 0.f;
  int r0 = min(max(y0, 0), HH - 1), r1 = min(max(y0 + 1, 0), HH - 1);
  int q0 = min(max(x0, 0), WW - 1), q1 = min(max(x0 + 1, 0), WW - 1);
  g.o00 = (r0 * WW + q0) * C1; g.o01 = (r0 * WW + q1) * C1;
  g.o10 = (r1 * WW + q0) * C1; g.o11 = (r1 * WW + q1) * C1;
  return g;
}

__global__ __launch_bounds__(256) void dconv_mfma_kernel(
    const ushort* __restrict__ xt, const float* __restrict__ offs,
    const ushort* __restrict__ wbf, const float* __restrict__ bias,
    float* __restrict__ out) {
  const int bid = blockIdx.x;                    // 0..1599
  const int b = bid & 15;
  const int tile = bid >> 4;                     // 0..99
  const int h0 = (tile / 5) * 4;
  const int w0 = (tile % 5) * 16;
  const int tid = threadIdx.x;
  const int lane = tid & 63;
  const int wave = tid >> 6;
  const int pl = lane & 15, cg = lane >> 4;
  const int spos = wave * 16 + pl;

  __shared__ float4 crd[9][64];                  // 9216 B
  __shared__ ushort s_t[4][64][8];               // 4 KB
  __shared__ ushort w_t[4][128][8];              // 8 KB

  // Phase A: per-(p,pos) coords
  for (int i = tid; i < 9 * 64; i += 256) {
    int p = i >> 6, pos = i & 63;
    int r = pos >> 4, cl = pos & 15;
    int ho = h0 + r, wo = w0 + cl;
    const float* obp = offs + (size_t)b * 18 * HWSZ + ho * WW + wo;
    float dy = obp[(size_t)(2 * p) * HWSZ];
    float dx = obp[(size_t)(2 * p + 1) * HWSZ];
    float py = (float)(ho - 1 + p / 3) + dy;
    float px = (float)(wo - 1 + p % 3) + dx;
    float y0f = floorf(py), x0f = floorf(px);
    crd[p][pos] = make_float4(y0f, x0f, py - y0f, px - x0f);
  }
  __syncthreads();

  f32x4 acc[8];
  #pragma unroll
  for (int mt = 0; mt < 8; mt++) acc[mt] = (f32x4){0.f, 0.f, 0.f, 0.f};

  const ushort* xtb = xt + (size_t)b * HWSZ * C1;

  // ---- pipeline prologue: geometry + loads for chunk 0
  Geo g = make_geo(crd[0][spos]);
  uint4 ca00, ca01, ca10, ca11, cw0, cw1;
  {
    const ushort* cp = xtb + cg * 8;             // c0 = 0
    ca00 = *(const uint4*)(cp + g.o00);
    ca01 = *(const uint4*)(cp + g.o01);
    ca10 = *(const uint4*)(cp + g.o10);
    ca11 = *(const uint4*)(cp + g.o11);
    cw0 = ((const uint4*)wbf)[tid];
    cw1 = ((const uint4*)wbf)[tid + 256];
  }

  #pragma unroll 4
  for (int kt = 0; kt < 36; ++kt) {
    // ---- issue next chunk's loads (overlaps this chunk's tail)
    Geo gn = g;
    uint4 na00, na01, na10, na11, nw0, nw1;
    if (kt < 35) {
      const int kn = kt + 1;
      if ((kn & 3) == 0) gn = make_geo(crd[kn >> 2][spos]);
      const ushort* np = xtb + ((kn & 3) << 5) + cg * 8;
      na00 = *(const uint4*)(np + gn.o00);
      na01 = *(const uint4*)(np + gn.o01);
      na10 = *(const uint4*)(np + gn.o10);
      na11 = *(const uint4*)(np + gn.o11);
      const uint4* wsrc = (const uint4*)(wbf + (size_t)kn * 4096);
      nw0 = wsrc[tid];
      nw1 = wsrc[tid + 256];
    }

    // ---- separable bilinear combine for current chunk
    union { uint4 v; ushort s[8]; } u00, u01, u10, u11, pk;
    u00.v = ca00; u01.v = ca01; u10.v = ca10; u11.v = ca11;
    #pragma unroll
    for (int j = 0; j < 8; ++j) {
      float top = g.fx0 * bf2f(u00.s[j]) + g.fx1 * bf2f(u01.s[j]);
      float bot = g.fx0 * bf2f(u10.s[j]) + g.fx1 * bf2f(u11.s[j]);
      pk.s[j] = f2bf(g.fy0 * top + g.fy1 * bot);
    }

    __syncthreads();   // all waves done reading previous tiles
    ((uint4*)s_t)[cg * 64 + spos] = pk.v;
    ((uint4*)w_t)[tid] = cw0;
    ((uint4*)w_t)[tid + 256] = cw1;
    __syncthreads();   // tiles ready

    // ---- MFMA: B frag (16 pos), 8 A frags (128 ch)
    const int q = lane >> 4, c15 = lane & 15;
    bf16x8 bfrag = *(const bf16x8*)&s_t[q][wave * 16 + c15][0];
    #pragma unroll
    for (int mt = 0; mt < 8; mt++) {
      bf16x8 afrag = *(const bf16x8*)&w_t[q][mt * 16 + c15][0];
      acc[mt] = __builtin_amdgcn_mfma_f32_16x16x32_bf16(afrag, bfrag, acc[mt], 0, 0, 0);
    }

    // ---- rotate pipeline registers
    g = gn;
    ca00 = na00; ca01 = na01; ca10 = na10; ca11 = na11;
    cw0 = nw0; cw1 = nw1;
  }

  // ---- epilogue
  {
    const int q = lane >> 4, c15 = lane & 15;
    const int ho = h0 + wave, wo = w0 + c15;
    #pragma unroll
    for (int mt = 0; mt < 8; mt++) {
      #pragma unroll
      for (int r = 0; r < 4; r++) {
        int ch = mt * 16 + q * 4 + r;
        out[((size_t)b * C2 + ch) * HWSZ + ho * WW + wo] = acc[mt][r] + bias[ch];
      }
    }
  }
}

// ---------------------------------------------------------------------------
extern "C" void kernel_launch(void* const* d_in, const int* in_sizes, int n_in,
                              void* d_out, int out_size, void* d_ws, size_t ws_size,
                              hipStream_t stream) {
  const float* x    = (const float*)d_in[0];   // (16,128,80,80)
  const float* ow   = (const float*)d_in[1];   // (18,128,3,3)
  const float* ob   = (const float*)d_in[2];   // (18,)
  const float* wgt  = (const float*)d_in[3];   // (128,128,3,3)
  const float* bias = (const float*)d_in[4];   // (128,)
  float* out = (float*)d_out;                  // (16,128,80,80)

  // workspace layout (xt first for 16B alignment)
  ushort* xt   = (ushort*)d_ws;                          // 26.2 MB
  float*  offs = (float*)((char*)d_ws + 26214400);       // 7.37 MB
  ushort* wbf  = (ushort*)((char*)d_ws + 26214400 + 7372800);           // 288 KB
  ushort* wobf = (ushort*)((char*)d_ws + 26214400 + 7372800 + 294912);  // 72 KB

  prep_kernel<<<dim3(720), dim3(256), 0, stream>>>(wgt, ow, wbf, wobf);
  xpose_kernel<<<dim3(100, 2, NB), dim3(256), 0, stream>>>(x, xt);
  offset_mfma_kernel<<<dim3(1600), dim3(256), 0, stream>>>(xt, wobf, ob, offs);
  dconv_mfma_kernel<<<dim3(1600), dim3(256), 0, stream>>>(xt, offs, wbf, bias, out);
}